// Round 1
// baseline (219.344 us; speedup 1.0000x reference)
//
#include <hip/hip_runtime.h>
#include <hip/hip_bf16.h>

typedef __bf16  bf16x8  __attribute__((ext_vector_type(8)));
typedef float   floatx4 __attribute__((ext_vector_type(4)));

#define ROWLEN      4096                  // floats per sample row (2048 sites x 2 phys)
#define NSTACK      1023                  // site-stack per half
#define B_SAMPLES   8192
#define FRAG_ELEMS  (2*64*4*64*8)         // 262144 bf16 = 512 KB

// ws layout: [0, 524288) bf16 weight fragments; then 32 floats of boundary vectors.
//
// Fragment layout (bf16x8 per lane, MFMA 16x16x32 B-operand order):
//   frag element f = (((h*64 + t)*4 + nt)*64 + lane)*8 + j
//   holds W_h[kk = t*32 + (lane>>4)*8 + j][n = nt*16 + (lane&15)]
// K is padded to 2048: h=0 covers x elements [0,2048) with kk<2 zero-weighted
// (site 0 is the boundary), h=1 covers [2048,4096) with s==1023 zero-weighted
// (site 2047 is the boundary). This keeps every A-load a 16B-aligned float4
// inside the sample's own row.

__global__ __launch_bounds__(256) void repack_kernel(
    const float* __restrict__ left_b, const float* __restrict__ left,
    const float* __restrict__ right,  const float* __restrict__ right_b,
    __bf16* __restrict__ wfrag, float* __restrict__ bvec)
{
    __shared__ float red[256];
    const int tid = threadIdx.x;

    // Frobenius norms of left[3] / right[3] (each 128 floats at flat offset 384)
    float v = (tid < 128) ? left[384 + tid] : right[384 + (tid - 128)];
    red[tid] = v * v;
    __syncthreads();
    for (int s = 64; s > 0; s >>= 1) {
        if ((tid & 127) < s) red[tid] += red[tid + s];
        __syncthreads();
    }
    const float invL = 1.0f / sqrtf(red[0]);
    const float invR = 1.0f / sqrtf(red[128]);

    // boundary vectors, row 2 normalized (left_b[2] = elems 4,5)
    if (blockIdx.x == 0 && tid < 32) {
        const float* src = (tid < 16) ? left_b : right_b;
        const int i = tid & 15;
        const float n2 = sqrtf(src[4]*src[4] + src[5]*src[5]);
        float val = src[i];
        if ((i >> 1) == 2) val /= n2;
        bvec[tid] = val;
    }

    // 64 blocks x 256 threads x 16 elems = 262144 fragment elements
    for (int u = 0; u < 16; ++u) {
        const int f    = (int)(blockIdx.x * 256 + tid) + u * 16384;
        const int j    = f & 7;
        const int lane = (f >> 3) & 63;
        const int nt   = (f >> 9) & 3;
        const int t    = (f >> 11) & 63;
        const int h    = (f >> 17) & 1;
        const int kk   = t * 32 + (lane >> 4) * 8 + j;
        const int n    = nt * 16 + (lane & 15);
        const int a    = n >> 3, bb = n & 7;
        const int p    = kk & 1;
        float val = 0.0f;
        if (h == 0) {
            const int s = (kk >> 1) - 1;            // site = kk>>1 in [1,1023]
            if (kk >= 2) {
                val = left[((s * 8 + a) * 8 + bb) * 2 + p];
                if (s == 3) val *= invL;
            }
        } else {
            const int s = kk >> 1;                  // site = 1024 + s
            if (s < NSTACK) {
                val = right[((s * 8 + a) * 8 + bb) * 2 + p];
                if (s == 3) val *= invR;
            }
        }
        wfrag[f] = (__bf16)val;
    }
}

__global__ __launch_bounds__(256) void mps_main_kernel(
    const float* __restrict__ x, const __bf16* __restrict__ wfrag,
    const float* __restrict__ bvec, float* __restrict__ out)
{
    __shared__ float lds[2][2][16][64];   // [half][kchunk][sample][n] = 16 KB
    const int tid  = threadIdx.x;
    const int wid  = tid >> 6;            // 4 waves: wave = (half, K-chunk)
    const int lane = tid & 63;
    const int h    = wid & 1;
    const int c    = wid >> 1;
    const int mcol = lane & 15;           // A row (sample) on load; D col on store
    const int q    = lane >> 4;
    const int blk  = blockIdx.x;

    const float* arow = x + (size_t)(blk * 16 + mcol) * ROWLEN
                          + h * 2048 + c * 1024 + q * 8;
    const bf16x8* bbase = (const bf16x8*)wfrag
                          + ((size_t)(h * 64 + c * 32) * 4) * 64 + lane;

    floatx4 acc0 = {0.f,0.f,0.f,0.f}, acc1 = {0.f,0.f,0.f,0.f};
    floatx4 acc2 = {0.f,0.f,0.f,0.f}, acc3 = {0.f,0.f,0.f,0.f};

#pragma unroll 2
    for (int tl = 0; tl < 32; ++tl) {
        const float4* ap = (const float4*)(arow + tl * 32);
        const float4 a0 = ap[0];
        const float4 a1 = ap[1];
        bf16x8 af;
        af[0] = (__bf16)a0.x; af[1] = (__bf16)a0.y;
        af[2] = (__bf16)a0.z; af[3] = (__bf16)a0.w;
        af[4] = (__bf16)a1.x; af[5] = (__bf16)a1.y;
        af[6] = (__bf16)a1.z; af[7] = (__bf16)a1.w;
        const bf16x8* bp = bbase + (size_t)tl * 256;
        acc0 = __builtin_amdgcn_mfma_f32_16x16x32_bf16(af, bp[0],   acc0, 0, 0, 0);
        acc1 = __builtin_amdgcn_mfma_f32_16x16x32_bf16(af, bp[64],  acc1, 0, 0, 0);
        acc2 = __builtin_amdgcn_mfma_f32_16x16x32_bf16(af, bp[128], acc2, 0, 0, 0);
        acc3 = __builtin_amdgcn_mfma_f32_16x16x32_bf16(af, bp[192], acc3, 0, 0, 0);
    }

    // C/D layout: lane holds D[row = q*4+i][col = lane&15]  (row = sample)
#pragma unroll
    for (int i = 0; i < 4; ++i) {
        lds[h][c][q * 4 + i][ 0 + mcol] = acc0[i];
        lds[h][c][q * 4 + i][16 + mcol] = acc1[i];
        lds[h][c][q * 4 + i][32 + mcol] = acc2[i];
        lds[h][c][q * 4 + i][48 + mcol] = acc3[i];
    }
    __syncthreads();

    if (tid < 128) {
        const int mm = tid >> 3;          // sample within block
        const int b  = tid & 7;           // bond index b
        const size_t k = (size_t)blk * 16 + mm;
        const float* xr = x + k * ROWLEN;
        const float x0 = xr[0],    x1 = xr[1];        // x[k, 0, :]
        const float y0 = xr[4094], y1 = xr[4095];     // x[k, 2047, :]
        float l = 0.f, r = 0.f;
#pragma unroll
        for (int a = 0; a < 8; ++a) {
            const float lv = bvec[a*2]      * x0 + bvec[a*2+1]      * x1;
            const float rv = bvec[16 + a*2] * y0 + bvec[16 + a*2+1] * y1;
            const int n = a * 8 + b;
            l += lv * (lds[0][0][mm][n] + lds[0][1][mm][n]);
            r += rv * (lds[1][0][mm][n] + lds[1][1][mm][n]);
        }
        float vv = l * r;
        vv += __shfl_xor(vv, 1);
        vv += __shfl_xor(vv, 2);
        vv += __shfl_xor(vv, 4);
        if (b == 0) out[k] = vv;
    }
}

extern "C" void kernel_launch(void* const* d_in, const int* in_sizes, int n_in,
                              void* d_out, int out_size, void* d_ws, size_t ws_size,
                              hipStream_t stream)
{
    const float* x       = (const float*)d_in[0];
    const float* left_b  = (const float*)d_in[1];
    const float* left    = (const float*)d_in[2];
    const float* right   = (const float*)d_in[3];
    const float* right_b = (const float*)d_in[4];

    __bf16* wfrag = (__bf16*)d_ws;
    float*  bvec  = (float*)((char*)d_ws + FRAG_ELEMS * sizeof(__bf16));
    float*  out   = (float*)d_out;

    hipLaunchKernelGGL(repack_kernel, dim3(64), dim3(256), 0, stream,
                       left_b, left, right, right_b, wfrag, bvec);
    hipLaunchKernelGGL(mps_main_kernel, dim3(B_SAMPLES / 16), dim3(256), 0, stream,
                       x, wfrag, bvec, out);
}

// Round 2
// 215.393 us; speedup vs baseline: 1.0183x; 1.0183x over previous
//
#include <hip/hip_runtime.h>
#include <hip/hip_bf16.h>

typedef __bf16  bf16x8  __attribute__((ext_vector_type(8)));
typedef float   floatx4 __attribute__((ext_vector_type(4)));

#define ROWLEN      4096                  // floats per sample row (2048 sites x 2 phys)
#define NSTACK      1023                  // site-stack per half
#define B_SAMPLES   8192
#define FRAG_ELEMS  (2*64*4*64*8)         // 262144 bf16 = 512 KB

// ws layout: [0, 524288) bf16 weight fragments; then 32 floats of boundary vectors.
//
// Fragment layout (bf16x8 per lane, MFMA 16x16x32 B-operand order):
//   frag element f = (((h*64 + t)*4 + nt)*64 + lane)*8 + j
//   holds W_h[kk = t*32 + (lane>>4)*8 + j][n = nt*16 + (lane&15)]
// K padded to 2048 per half: h=0 zero-weights kk<2 (site 0 = boundary),
// h=1 zero-weights s==1023 (site 2047 = boundary). Every A-load is a
// 16B-aligned float4 inside the sample's own contiguous row.

__global__ __launch_bounds__(256) void repack_kernel(
    const float* __restrict__ left_b, const float* __restrict__ left,
    const float* __restrict__ right,  const float* __restrict__ right_b,
    __bf16* __restrict__ wfrag, float* __restrict__ bvec)
{
    __shared__ float red[256];
    const int tid = threadIdx.x;

    // Frobenius norms of left[3] / right[3] (each 128 floats at flat offset 384)
    float v = (tid < 128) ? left[384 + tid] : right[384 + (tid - 128)];
    red[tid] = v * v;
    __syncthreads();
    for (int s = 64; s > 0; s >>= 1) {
        if ((tid & 127) < s) red[tid] += red[tid + s];
        __syncthreads();
    }
    const float invL = 1.0f / sqrtf(red[0]);
    const float invR = 1.0f / sqrtf(red[128]);

    // boundary vectors, row 2 normalized (left_b[2] = elems 4,5)
    if (blockIdx.x == 0 && tid < 32) {
        const float* src = (tid < 16) ? left_b : right_b;
        const int i = tid & 15;
        const float n2 = sqrtf(src[4]*src[4] + src[5]*src[5]);
        float val = src[i];
        if ((i >> 1) == 2) val /= n2;
        bvec[tid] = val;
    }

    // 64 blocks x 256 threads x 16 elems = 262144 fragment elements
    for (int u = 0; u < 16; ++u) {
        const int f    = (int)(blockIdx.x * 256 + tid) + u * 16384;
        const int j    = f & 7;
        const int lane = (f >> 3) & 63;
        const int nt   = (f >> 9) & 3;
        const int t    = (f >> 11) & 63;
        const int h    = (f >> 17) & 1;
        const int kk   = t * 32 + (lane >> 4) * 8 + j;
        const int n    = nt * 16 + (lane & 15);
        const int a    = n >> 3, bb = n & 7;
        const int p    = kk & 1;
        float val = 0.0f;
        if (h == 0) {
            const int s = (kk >> 1) - 1;            // site = kk>>1 in [1,1023]
            if (kk >= 2) {
                val = left[((s * 8 + a) * 8 + bb) * 2 + p];
                if (s == 3) val *= invL;
            }
        } else {
            const int s = kk >> 1;                  // site = 1024 + s
            if (s < NSTACK) {
                val = right[((s * 8 + a) * 8 + bb) * 2 + p];
                if (s == 3) val *= invR;
            }
        }
        wfrag[f] = (__bf16)val;
    }
}

// 512 blocks x 512 threads. Wave w (0..7): h = w&1, K-chunk c = w>>1 (K=512 each).
// 16 samples per block. 16 waves/CU for latency hiding.
__global__ __launch_bounds__(512, 4) void mps_main_kernel(
    const float* __restrict__ x, const __bf16* __restrict__ wfrag,
    const float* __restrict__ bvec, float* __restrict__ out)
{
    __shared__ float lds[2][4][16][65];   // [half][kchunk][sample][n], padded
    const int tid  = threadIdx.x;
    const int wid  = tid >> 6;            // 8 waves
    const int lane = tid & 63;
    const int h    = wid & 1;
    const int c    = wid >> 1;            // 0..3
    const int mcol = lane & 15;           // A row (sample) on load; D col on store
    const int q    = lane >> 4;
    const int blk  = blockIdx.x;

    const float* arow = x + (size_t)(blk * 16 + mcol) * ROWLEN
                          + h * 2048 + c * 512 + q * 8;
    const bf16x8* bbase = (const bf16x8*)wfrag
                          + ((size_t)(h * 64 + c * 16) * 4) * 64 + lane;

    floatx4 acc0 = {0.f,0.f,0.f,0.f}, acc1 = {0.f,0.f,0.f,0.f};
    floatx4 acc2 = {0.f,0.f,0.f,0.f}, acc3 = {0.f,0.f,0.f,0.f};

#pragma unroll 2
    for (int tl = 0; tl < 16; ++tl) {
        const floatx4* ap = (const floatx4*)(arow + tl * 32);
        const floatx4 a0 = __builtin_nontemporal_load(ap);
        const floatx4 a1 = __builtin_nontemporal_load(ap + 1);
        bf16x8 af;
        af[0] = (__bf16)a0[0]; af[1] = (__bf16)a0[1];
        af[2] = (__bf16)a0[2]; af[3] = (__bf16)a0[3];
        af[4] = (__bf16)a1[0]; af[5] = (__bf16)a1[1];
        af[6] = (__bf16)a1[2]; af[7] = (__bf16)a1[3];
        const bf16x8* bp = bbase + (size_t)tl * 256;
        acc0 = __builtin_amdgcn_mfma_f32_16x16x32_bf16(af, bp[0],   acc0, 0, 0, 0);
        acc1 = __builtin_amdgcn_mfma_f32_16x16x32_bf16(af, bp[64],  acc1, 0, 0, 0);
        acc2 = __builtin_amdgcn_mfma_f32_16x16x32_bf16(af, bp[128], acc2, 0, 0, 0);
        acc3 = __builtin_amdgcn_mfma_f32_16x16x32_bf16(af, bp[192], acc3, 0, 0, 0);
    }

    // C/D layout: lane holds D[row = q*4+i][col = lane&15]  (row = sample)
#pragma unroll
    for (int i = 0; i < 4; ++i) {
        lds[h][c][q * 4 + i][ 0 + mcol] = acc0[i];
        lds[h][c][q * 4 + i][16 + mcol] = acc1[i];
        lds[h][c][q * 4 + i][32 + mcol] = acc2[i];
        lds[h][c][q * 4 + i][48 + mcol] = acc3[i];
    }
    __syncthreads();

    if (tid < 128) {
        const int mm = tid >> 3;          // sample within block
        const int b  = tid & 7;           // bond index b
        const size_t k = (size_t)blk * 16 + mm;
        const float* xr = x + k * ROWLEN;
        const float x0 = xr[0],    x1 = xr[1];        // x[k, 0, :]
        const float y0 = xr[4094], y1 = xr[4095];     // x[k, 2047, :]
        float l = 0.f, r = 0.f;
#pragma unroll
        for (int a = 0; a < 8; ++a) {
            const float lv = bvec[a*2]      * x0 + bvec[a*2+1]      * x1;
            const float rv = bvec[16 + a*2] * y0 + bvec[16 + a*2+1] * y1;
            const int n = a * 8 + b;
            const float ls = lds[0][0][mm][n] + lds[0][1][mm][n]
                           + lds[0][2][mm][n] + lds[0][3][mm][n];
            const float rs = lds[1][0][mm][n] + lds[1][1][mm][n]
                           + lds[1][2][mm][n] + lds[1][3][mm][n];
            l += lv * ls;
            r += rv * rs;
        }
        float vv = l * r;
        vv += __shfl_xor(vv, 1);
        vv += __shfl_xor(vv, 2);
        vv += __shfl_xor(vv, 4);
        if (b == 0) out[k] = vv;
    }
}

extern "C" void kernel_launch(void* const* d_in, const int* in_sizes, int n_in,
                              void* d_out, int out_size, void* d_ws, size_t ws_size,
                              hipStream_t stream)
{
    const float* x       = (const float*)d_in[0];
    const float* left_b  = (const float*)d_in[1];
    const float* left    = (const float*)d_in[2];
    const float* right   = (const float*)d_in[3];
    const float* right_b = (const float*)d_in[4];

    __bf16* wfrag = (__bf16*)d_ws;
    float*  bvec  = (float*)((char*)d_ws + FRAG_ELEMS * sizeof(__bf16));
    float*  out   = (float*)d_out;

    hipLaunchKernelGGL(repack_kernel, dim3(64), dim3(256), 0, stream,
                       left_b, left, right, right_b, wfrag, bvec);
    hipLaunchKernelGGL(mps_main_kernel, dim3(B_SAMPLES / 16), dim3(512), 0, stream,
                       x, wfrag, bvec, out);
}

// Round 3
// 208.152 us; speedup vs baseline: 1.0538x; 1.0348x over previous
//
#include <hip/hip_runtime.h>
#include <hip/hip_bf16.h>

typedef __bf16  bf16x8  __attribute__((ext_vector_type(8)));
typedef float   floatx4 __attribute__((ext_vector_type(4)));

#define ROWLEN      4096                  // floats per sample row (2048 sites x 2 phys)
#define B_SAMPLES   8192
#define FRAG_ELEMS  (2*64*4*64*8)         // 262144 bf16 = 512 KB

// ws layout: [0, 524288) bf16 weight fragments (MFMA B-operand order).
//
// Fragment layout (bf16x8 per lane, MFMA 16x16x32 B-operand order):
//   frag g = ((h*64 + t)*4 + nt)*64 + lane ; element j (0..7)
//   holds W_h[kk = t*32 + (lane>>4)*8 + j][n = nt*16 + (lane&15)]
// K padded to 2048 per half: h=0 zero-weights kk<2 (site 0 = boundary),
// h=1 zero-weights site 2047 (boundary). Every A-load in main is a
// 16B-aligned float4 inside the sample's own contiguous row.
//
// Weight element for kk: p = kk&1; h=0: s = (kk>>1)-1 (valid kk>=2);
// h=1: s = kk>>1 (valid s<1023). W[s][a=n>>3][b=n&7][p], row s==3 scaled
// by 1/||.||_F of slice 3.

// 128 blocks x 256 threads: one thread per fragment (8 bf16 = 16 B store).
__global__ __launch_bounds__(256) void repack_kernel(
    const float* __restrict__ left, const float* __restrict__ right,
    __bf16* __restrict__ wfrag)
{
    __shared__ float red[256];
    const int tid = threadIdx.x;

    // Frobenius norms of left[3] / right[3] (each 128 floats at flat offset 384)
    float v = (tid < 128) ? left[384 + tid] : right[384 + (tid - 128)];
    red[tid] = v * v;
    __syncthreads();
    for (int s = 64; s > 0; s >>= 1) {
        if ((tid & 127) < s) red[tid] += red[tid + s];
        __syncthreads();
    }
    const float invL = 1.0f / sqrtf(red[0]);
    const float invR = 1.0f / sqrtf(red[128]);

    const int g    = (int)(blockIdx.x * 256) + tid;   // fragment index [0,32768)
    const int lane = g & 63;
    const int nt   = (g >> 6) & 3;
    const int t    = (g >> 8) & 63;
    const int h    = (g >> 14) & 1;
    const int kk0  = t * 32 + (lane >> 4) * 8;        // first kk of this frag
    const int n    = nt * 16 + (lane & 15);
    const int a    = n >> 3, bb = n & 7;
    const float* W = (h == 0) ? left : right;

    bf16x8 frag;
#pragma unroll
    for (int si = 0; si < 4; ++si) {
        const int kk = kk0 + si * 2;                  // p=0 element; p=1 is kk+1
        int s;  bool valid;
        if (h == 0) { s = (kk >> 1) - 1; valid = (kk >= 2); }
        else        { s = (kk >> 1);     valid = (s < 1023); }
        float w0 = 0.f, w1 = 0.f;
        if (valid) {
            const float* wp = W + ((s * 8 + a) * 8 + bb) * 2;
            w0 = wp[0]; w1 = wp[1];
            if (s == 3) { const float sc = (h == 0) ? invL : invR; w0 *= sc; w1 *= sc; }
        }
        frag[si * 2]     = (__bf16)w0;
        frag[si * 2 + 1] = (__bf16)w1;
    }
    ((bf16x8*)wfrag)[g] = frag;
}

// 512 blocks x 512 threads. Wave w (0..7): h = w&1, K-chunk c = w>>1 (K=512 each).
// 16 samples per block; 16 waves/CU.
__global__ __launch_bounds__(512, 4) void mps_main_kernel(
    const float* __restrict__ x, const __bf16* __restrict__ wfrag,
    const float* __restrict__ left_b, const float* __restrict__ right_b,
    float* __restrict__ out)
{
    __shared__ float lds[2][4][16][65];   // [half][kchunk][sample][n], padded
    const int tid  = threadIdx.x;
    const int wid  = tid >> 6;            // 8 waves
    const int lane = tid & 63;
    const int h    = wid & 1;
    const int c    = wid >> 1;            // 0..3
    const int mcol = lane & 15;           // A row (sample) on load; D col on store
    const int q    = lane >> 4;
    const int blk  = blockIdx.x;

    const float* arow = x + (size_t)(blk * 16 + mcol) * ROWLEN
                          + h * 2048 + c * 512 + q * 8;
    const bf16x8* bbase = (const bf16x8*)wfrag
                          + ((size_t)(h * 64 + c * 16) * 4) * 64 + lane;

    floatx4 acc0 = {0.f,0.f,0.f,0.f}, acc1 = {0.f,0.f,0.f,0.f};
    floatx4 acc2 = {0.f,0.f,0.f,0.f}, acc3 = {0.f,0.f,0.f,0.f};

#pragma unroll 2
    for (int tl = 0; tl < 16; ++tl) {
        const floatx4* ap = (const floatx4*)(arow + tl * 32);
        const floatx4 a0 = __builtin_nontemporal_load(ap);
        const floatx4 a1 = __builtin_nontemporal_load(ap + 1);
        bf16x8 af;
        af[0] = (__bf16)a0[0]; af[1] = (__bf16)a0[1];
        af[2] = (__bf16)a0[2]; af[3] = (__bf16)a0[3];
        af[4] = (__bf16)a1[0]; af[5] = (__bf16)a1[1];
        af[6] = (__bf16)a1[2]; af[7] = (__bf16)a1[3];
        const bf16x8* bp = bbase + (size_t)tl * 256;
        acc0 = __builtin_amdgcn_mfma_f32_16x16x32_bf16(af, bp[0],   acc0, 0, 0, 0);
        acc1 = __builtin_amdgcn_mfma_f32_16x16x32_bf16(af, bp[64],  acc1, 0, 0, 0);
        acc2 = __builtin_amdgcn_mfma_f32_16x16x32_bf16(af, bp[128], acc2, 0, 0, 0);
        acc3 = __builtin_amdgcn_mfma_f32_16x16x32_bf16(af, bp[192], acc3, 0, 0, 0);
    }

    // C/D layout: lane holds D[row = q*4+i][col = lane&15]  (row = sample)
#pragma unroll
    for (int i = 0; i < 4; ++i) {
        lds[h][c][q * 4 + i][ 0 + mcol] = acc0[i];
        lds[h][c][q * 4 + i][16 + mcol] = acc1[i];
        lds[h][c][q * 4 + i][32 + mcol] = acc2[i];
        lds[h][c][q * 4 + i][48 + mcol] = acc3[i];
    }
    __syncthreads();

    if (tid < 128) {
        const int mm = tid >> 3;          // sample within block
        const int b  = tid & 7;           // bond index b
        const size_t k = (size_t)blk * 16 + mm;
        const float* xr = x + k * ROWLEN;
        const float x0 = xr[0],    x1 = xr[1];        // x[k, 0, :]
        const float y0 = xr[4094], y1 = xr[4095];     // x[k, 2047, :]
        // boundary vectors inline (row 2 normalized), wave-uniform loads
        const float lbn = 1.0f / sqrtf(left_b[4]*left_b[4] + left_b[5]*left_b[5]);
        const float rbn = 1.0f / sqrtf(right_b[4]*right_b[4] + right_b[5]*right_b[5]);
        float l = 0.f, r = 0.f;
#pragma unroll
        for (int a = 0; a < 8; ++a) {
            float lv = left_b[a*2]  * x0 + left_b[a*2+1]  * x1;
            float rv = right_b[a*2] * y0 + right_b[a*2+1] * y1;
            if (a == 2) { lv *= lbn; rv *= rbn; }
            const int n = a * 8 + b;
            const float ls = lds[0][0][mm][n] + lds[0][1][mm][n]
                           + lds[0][2][mm][n] + lds[0][3][mm][n];
            const float rs = lds[1][0][mm][n] + lds[1][1][mm][n]
                           + lds[1][2][mm][n] + lds[1][3][mm][n];
            l += lv * ls;
            r += rv * rs;
        }
        float vv = l * r;
        vv += __shfl_xor(vv, 1);
        vv += __shfl_xor(vv, 2);
        vv += __shfl_xor(vv, 4);
        if (b == 0) out[k] = vv;
    }
}

extern "C" void kernel_launch(void* const* d_in, const int* in_sizes, int n_in,
                              void* d_out, int out_size, void* d_ws, size_t ws_size,
                              hipStream_t stream)
{
    const float* x       = (const float*)d_in[0];
    const float* left_b  = (const float*)d_in[1];
    const float* left    = (const float*)d_in[2];
    const float* right   = (const float*)d_in[3];
    const float* right_b = (const float*)d_in[4];

    __bf16* wfrag = (__bf16*)d_ws;
    float*  out   = (float*)d_out;

    hipLaunchKernelGGL(repack_kernel, dim3(128), dim3(256), 0, stream,
                       left, right, wfrag);
    hipLaunchKernelGGL(mps_main_kernel, dim3(B_SAMPLES / 16), dim3(512), 0, stream,
                       x, wfrag, left_b, right_b, out);
}

// Round 4
// 203.249 us; speedup vs baseline: 1.0792x; 1.0241x over previous
//
#include <hip/hip_runtime.h>
#include <hip/hip_bf16.h>

typedef __bf16  bf16x8  __attribute__((ext_vector_type(8)));
typedef float   floatx4 __attribute__((ext_vector_type(4)));

#define ROWLEN      4096                  // floats per sample row (2048 sites x 2 phys)
#define B_SAMPLES   8192
#define FRAG_ELEMS  (2*64*4*64*8)         // 262144 bf16 = 512 KB

// ws layout: [0, 524288) bf16 weight fragments (MFMA B-operand order).
//
// Fragment layout (bf16x8 per lane, MFMA 16x16x32 B-operand order):
//   frag g = ((h*64 + t)*4 + nt)*64 + lane ; element j (0..7)
//   holds W_h[kk = t*32 + (lane>>4)*8 + j][n = nt*16 + (lane&15)]
// K padded to 2048 per half: h=0 zero-weights kk<2 (site 0 = boundary),
// h=1 zero-weights site 2047 (boundary). Every A-load in main is a
// 16B-aligned float4 inside the sample's own contiguous row.

// 128 blocks x 256 threads: one thread per fragment (8 bf16 = 16 B store).
__global__ __launch_bounds__(256) void repack_kernel(
    const float* __restrict__ left, const float* __restrict__ right,
    __bf16* __restrict__ wfrag)
{
    __shared__ float red[256];
    const int tid = threadIdx.x;

    // Frobenius norms of left[3] / right[3] (each 128 floats at flat offset 384)
    float v = (tid < 128) ? left[384 + tid] : right[384 + (tid - 128)];
    red[tid] = v * v;
    __syncthreads();
    for (int s = 64; s > 0; s >>= 1) {
        if ((tid & 127) < s) red[tid] += red[tid + s];
        __syncthreads();
    }
    const float invL = 1.0f / sqrtf(red[0]);
    const float invR = 1.0f / sqrtf(red[128]);

    const int g    = (int)(blockIdx.x * 256) + tid;   // fragment index [0,32768)
    const int lane = g & 63;
    const int nt   = (g >> 6) & 3;
    const int t    = (g >> 8) & 63;
    const int h    = (g >> 14) & 1;
    const int kk0  = t * 32 + (lane >> 4) * 8;        // first kk of this frag
    const int n    = nt * 16 + (lane & 15);
    const int a    = n >> 3, bb = n & 7;
    const float* W = (h == 0) ? left : right;

    bf16x8 frag;
#pragma unroll
    for (int si = 0; si < 4; ++si) {
        const int kk = kk0 + si * 2;                  // p=0 element; p=1 is kk+1
        int s;  bool valid;
        if (h == 0) { s = (kk >> 1) - 1; valid = (kk >= 2); }
        else        { s = (kk >> 1);     valid = (s < 1023); }
        float w0 = 0.f, w1 = 0.f;
        if (valid) {
            const float* wp = W + ((s * 8 + a) * 8 + bb) * 2;
            w0 = wp[0]; w1 = wp[1];
            if (s == 3) { const float sc = (h == 0) ? invL : invR; w0 *= sc; w1 *= sc; }
        }
        frag[si * 2]     = (__bf16)w0;
        frag[si * 2 + 1] = (__bf16)w1;
    }
    ((bf16x8*)wfrag)[g] = frag;
}

// 256 blocks x 512 threads. Wave w (0..7): h = w&1, K-chunk c = w>>1 (K=512).
// 32 samples per block: each wave computes TWO M=16 tiles sharing the same
// B-fragments (halves wfrag L2 traffic per sample, 8 MFMAs : 4 B-loads).
__global__ __launch_bounds__(512, 2) void mps_main_kernel(
    const float* __restrict__ x, const __hip_bfloat16* __restrict__ wf_dummy,
    const __bf16* __restrict__ wfrag,
    const float* __restrict__ left_b, const float* __restrict__ right_b,
    float* __restrict__ out)
{
    __shared__ float lds[2][4][32][65];   // [half][kchunk][sample][n], padded
    const int tid  = threadIdx.x;
    const int wid  = tid >> 6;            // 8 waves
    const int lane = tid & 63;
    const int h    = wid & 1;
    const int c    = wid >> 1;            // 0..3
    const int mcol = lane & 15;           // A row (sample) on load; D col on store
    const int q    = lane >> 4;
    const int blk  = blockIdx.x;

    const float* arow0 = x + (size_t)(blk * 32 + mcol) * ROWLEN
                           + h * 2048 + c * 512 + q * 8;
    const float* arow1 = arow0 + (size_t)16 * ROWLEN;
    const bf16x8* bbase = (const bf16x8*)wfrag
                          + ((size_t)(h * 64 + c * 16) * 4) * 64 + lane;

    floatx4 accA0 = {0.f,0.f,0.f,0.f}, accA1 = {0.f,0.f,0.f,0.f};
    floatx4 accA2 = {0.f,0.f,0.f,0.f}, accA3 = {0.f,0.f,0.f,0.f};
    floatx4 accB0 = {0.f,0.f,0.f,0.f}, accB1 = {0.f,0.f,0.f,0.f};
    floatx4 accB2 = {0.f,0.f,0.f,0.f}, accB3 = {0.f,0.f,0.f,0.f};

#pragma unroll 2
    for (int tl = 0; tl < 16; ++tl) {
        const floatx4* ap0 = (const floatx4*)(arow0 + tl * 32);
        const floatx4* ap1 = (const floatx4*)(arow1 + tl * 32);
        const floatx4 a0 = __builtin_nontemporal_load(ap0);
        const floatx4 a1 = __builtin_nontemporal_load(ap0 + 1);
        const floatx4 b0 = __builtin_nontemporal_load(ap1);
        const floatx4 b1 = __builtin_nontemporal_load(ap1 + 1);
        bf16x8 af0, af1;
        af0[0] = (__bf16)a0[0]; af0[1] = (__bf16)a0[1];
        af0[2] = (__bf16)a0[2]; af0[3] = (__bf16)a0[3];
        af0[4] = (__bf16)a1[0]; af0[5] = (__bf16)a1[1];
        af0[6] = (__bf16)a1[2]; af0[7] = (__bf16)a1[3];
        af1[0] = (__bf16)b0[0]; af1[1] = (__bf16)b0[1];
        af1[2] = (__bf16)b0[2]; af1[3] = (__bf16)b0[3];
        af1[4] = (__bf16)b1[0]; af1[5] = (__bf16)b1[1];
        af1[6] = (__bf16)b1[2]; af1[7] = (__bf16)b1[3];
        const bf16x8* bp = bbase + (size_t)tl * 256;
        const bf16x8 w0 = bp[0], w1 = bp[64], w2 = bp[128], w3 = bp[192];
        accA0 = __builtin_amdgcn_mfma_f32_16x16x32_bf16(af0, w0, accA0, 0, 0, 0);
        accB0 = __builtin_amdgcn_mfma_f32_16x16x32_bf16(af1, w0, accB0, 0, 0, 0);
        accA1 = __builtin_amdgcn_mfma_f32_16x16x32_bf16(af0, w1, accA1, 0, 0, 0);
        accB1 = __builtin_amdgcn_mfma_f32_16x16x32_bf16(af1, w1, accB1, 0, 0, 0);
        accA2 = __builtin_amdgcn_mfma_f32_16x16x32_bf16(af0, w2, accA2, 0, 0, 0);
        accB2 = __builtin_amdgcn_mfma_f32_16x16x32_bf16(af1, w2, accB2, 0, 0, 0);
        accA3 = __builtin_amdgcn_mfma_f32_16x16x32_bf16(af0, w3, accA3, 0, 0, 0);
        accB3 = __builtin_amdgcn_mfma_f32_16x16x32_bf16(af1, w3, accB3, 0, 0, 0);
    }

    // C/D layout: lane holds D[row = q*4+i][col = lane&15]; row = sample-in-tile
#pragma unroll
    for (int i = 0; i < 4; ++i) {
        const int r0 = q * 4 + i;
        lds[h][c][r0][ 0 + mcol] = accA0[i];
        lds[h][c][r0][16 + mcol] = accA1[i];
        lds[h][c][r0][32 + mcol] = accA2[i];
        lds[h][c][r0][48 + mcol] = accA3[i];
        lds[h][c][16 + r0][ 0 + mcol] = accB0[i];
        lds[h][c][16 + r0][16 + mcol] = accB1[i];
        lds[h][c][16 + r0][32 + mcol] = accB2[i];
        lds[h][c][16 + r0][48 + mcol] = accB3[i];
    }
    __syncthreads();

    if (tid < 256) {
        const int mm = tid >> 3;          // sample within block (0..31)
        const int b  = tid & 7;           // bond index b
        const size_t k = (size_t)blk * 32 + mm;
        const float* xr = x + k * ROWLEN;
        const float x0 = xr[0],    x1 = xr[1];        // x[k, 0, :]
        const float y0 = xr[4094], y1 = xr[4095];     // x[k, 2047, :]
        // boundary vectors inline (row 2 normalized), wave-uniform loads
        const float lbn = 1.0f / sqrtf(left_b[4]*left_b[4] + left_b[5]*left_b[5]);
        const float rbn = 1.0f / sqrtf(right_b[4]*right_b[4] + right_b[5]*right_b[5]);
        float l = 0.f, r = 0.f;
#pragma unroll
        for (int a = 0; a < 8; ++a) {
            float lv = left_b[a*2]  * x0 + left_b[a*2+1]  * x1;
            float rv = right_b[a*2] * y0 + right_b[a*2+1] * y1;
            if (a == 2) { lv *= lbn; rv *= rbn; }
            const int n = a * 8 + b;
            const float ls = lds[0][0][mm][n] + lds[0][1][mm][n]
                           + lds[0][2][mm][n] + lds[0][3][mm][n];
            const float rs = lds[1][0][mm][n] + lds[1][1][mm][n]
                           + lds[1][2][mm][n] + lds[1][3][mm][n];
            l += lv * ls;
            r += rv * rs;
        }
        float vv = l * r;
        vv += __shfl_xor(vv, 1);
        vv += __shfl_xor(vv, 2);
        vv += __shfl_xor(vv, 4);
        if (b == 0) out[k] = vv;
    }
}

extern "C" void kernel_launch(void* const* d_in, const int* in_sizes, int n_in,
                              void* d_out, int out_size, void* d_ws, size_t ws_size,
                              hipStream_t stream)
{
    const float* x       = (const float*)d_in[0];
    const float* left_b  = (const float*)d_in[1];
    const float* left    = (const float*)d_in[2];
    const float* right   = (const float*)d_in[3];
    const float* right_b = (const float*)d_in[4];

    __bf16* wfrag = (__bf16*)d_ws;
    float*  out   = (float*)d_out;

    hipLaunchKernelGGL(repack_kernel, dim3(128), dim3(256), 0, stream,
                       left, right, wfrag);
    hipLaunchKernelGGL(mps_main_kernel, dim3(B_SAMPLES / 32), dim3(512), 0, stream,
                       x, (const __hip_bfloat16*)wfrag, wfrag, left_b, right_b, out);
}

// Round 5
// 199.931 us; speedup vs baseline: 1.0971x; 1.0166x over previous
//
#include <hip/hip_runtime.h>
#include <hip/hip_bf16.h>

typedef __bf16  bf16x8  __attribute__((ext_vector_type(8)));
typedef float   floatx4 __attribute__((ext_vector_type(4)));

#define ROWLEN      4096                  // floats per sample row (2048 sites x 2 phys)
#define B_SAMPLES   8192
#define FRAG_ELEMS  (2*64*4*64*8)         // 262144 bf16 = 512 KB

// ws layout: [0, 524288) bf16 weight fragments (MFMA B-operand order).
//
// Fragment layout (bf16x8 per lane, MFMA 16x16x32 B-operand order):
//   frag g = ((h*64 + t)*4 + nt)*64 + lane ; element j (0..7)
//   holds W_h[kk = t*32 + (lane>>4)*8 + j][n = nt*16 + (lane&15)]
// K padded to 2048 per half: h=0 zero-weights kk<2 (site 0 = boundary),
// h=1 zero-weights site 2047 (boundary). Every A-load in main is a
// 16B-aligned float4 inside the sample's own contiguous row.

// 128 blocks x 256 threads: one thread per fragment (8 bf16 = 16 B store).
__global__ __launch_bounds__(256) void repack_kernel(
    const float* __restrict__ left, const float* __restrict__ right,
    __bf16* __restrict__ wfrag)
{
    __shared__ float norms[2];
    const int tid  = threadIdx.x;
    const int wv   = tid >> 6;
    const int ln   = tid & 63;

    // Frobenius norms of left[3]/right[3] (128 floats each at offset 384):
    // wave 0 -> left, wave 1 -> right, shuffle reduction, single sync.
    if (wv < 2) {
        const float* W = (wv == 0) ? left : right;
        float a = W[384 + ln], b = W[384 + 64 + ln];
        float s = a * a + b * b;
        s += __shfl_xor(s, 1);  s += __shfl_xor(s, 2);  s += __shfl_xor(s, 4);
        s += __shfl_xor(s, 8);  s += __shfl_xor(s, 16); s += __shfl_xor(s, 32);
        if (ln == 0) norms[wv] = 1.0f / sqrtf(s);
    }
    __syncthreads();
    const float invL = norms[0];
    const float invR = norms[1];

    const int g    = (int)(blockIdx.x * 256) + tid;   // fragment index [0,32768)
    const int lane = g & 63;
    const int nt   = (g >> 6) & 3;
    const int t    = (g >> 8) & 63;
    const int h    = (g >> 14) & 1;
    const int kk0  = t * 32 + (lane >> 4) * 8;        // first kk of this frag
    const int n    = nt * 16 + (lane & 15);
    const int a    = n >> 3, bb = n & 7;
    const float* W = (h == 0) ? left : right;

    bf16x8 frag;
#pragma unroll
    for (int si = 0; si < 4; ++si) {
        const int kk = kk0 + si * 2;                  // p=0 element; p=1 is kk+1
        int s;  bool valid;
        if (h == 0) { s = (kk >> 1) - 1; valid = (kk >= 2); }
        else        { s = (kk >> 1);     valid = (s < 1023); }
        float w0 = 0.f, w1 = 0.f;
        if (valid) {
            const float* wp = W + ((s * 8 + a) * 8 + bb) * 2;
            w0 = wp[0]; w1 = wp[1];
            if (s == 3) { const float sc = (h == 0) ? invL : invR; w0 *= sc; w1 *= sc; }
        }
        frag[si * 2]     = (__bf16)w0;
        frag[si * 2 + 1] = (__bf16)w1;
    }
    ((bf16x8*)wfrag)[g] = frag;
}

// 256 blocks x 512 threads. Wave w (0..7): h = w&1, K-chunk c = w>>1 (K=512).
// 32 samples per block: each wave computes TWO M=16 tiles sharing the same
// B-fragments (halves wfrag L2 traffic per sample, 8 MFMAs : 4 B-loads).
__global__ __launch_bounds__(512, 2) void mps_main_kernel(
    const float* __restrict__ x, const __bf16* __restrict__ wfrag,
    const float* __restrict__ left_b, const float* __restrict__ right_b,
    float* __restrict__ out)
{
    __shared__ float lds[2][4][32][65];   // [half][kchunk][sample][n], padded
    const int tid  = threadIdx.x;
    const int wid  = tid >> 6;            // 8 waves
    const int lane = tid & 63;
    const int h    = wid & 1;
    const int c    = wid >> 1;            // 0..3
    const int mcol = lane & 15;           // A row (sample) on load; D col on store
    const int q    = lane >> 4;
    const int blk  = blockIdx.x;

    const float* arow0 = x + (size_t)(blk * 32 + mcol) * ROWLEN
                           + h * 2048 + c * 512 + q * 8;
    const float* arow1 = arow0 + (size_t)16 * ROWLEN;
    const bf16x8* bbase = (const bf16x8*)wfrag
                          + ((size_t)(h * 64 + c * 16) * 4) * 64 + lane;

    floatx4 accA0 = {0.f,0.f,0.f,0.f}, accA1 = {0.f,0.f,0.f,0.f};
    floatx4 accA2 = {0.f,0.f,0.f,0.f}, accA3 = {0.f,0.f,0.f,0.f};
    floatx4 accB0 = {0.f,0.f,0.f,0.f}, accB1 = {0.f,0.f,0.f,0.f};
    floatx4 accB2 = {0.f,0.f,0.f,0.f}, accB3 = {0.f,0.f,0.f,0.f};

#pragma unroll 4
    for (int tl = 0; tl < 16; ++tl) {
        const floatx4* ap0 = (const floatx4*)(arow0 + tl * 32);
        const floatx4* ap1 = (const floatx4*)(arow1 + tl * 32);
        const floatx4 a0 = __builtin_nontemporal_load(ap0);
        const floatx4 a1 = __builtin_nontemporal_load(ap0 + 1);
        const floatx4 b0 = __builtin_nontemporal_load(ap1);
        const floatx4 b1 = __builtin_nontemporal_load(ap1 + 1);
        bf16x8 af0, af1;
        af0[0] = (__bf16)a0[0]; af0[1] = (__bf16)a0[1];
        af0[2] = (__bf16)a0[2]; af0[3] = (__bf16)a0[3];
        af0[4] = (__bf16)a1[0]; af0[5] = (__bf16)a1[1];
        af0[6] = (__bf16)a1[2]; af0[7] = (__bf16)a1[3];
        af1[0] = (__bf16)b0[0]; af1[1] = (__bf16)b0[1];
        af1[2] = (__bf16)b0[2]; af1[3] = (__bf16)b0[3];
        af1[4] = (__bf16)b1[0]; af1[5] = (__bf16)b1[1];
        af1[6] = (__bf16)b1[2]; af1[7] = (__bf16)b1[3];
        const bf16x8* bp = bbase + (size_t)tl * 256;
        const bf16x8 w0 = bp[0], w1 = bp[64], w2 = bp[128], w3 = bp[192];
        accA0 = __builtin_amdgcn_mfma_f32_16x16x32_bf16(af0, w0, accA0, 0, 0, 0);
        accB0 = __builtin_amdgcn_mfma_f32_16x16x32_bf16(af1, w0, accB0, 0, 0, 0);
        accA1 = __builtin_amdgcn_mfma_f32_16x16x32_bf16(af0, w1, accA1, 0, 0, 0);
        accB1 = __builtin_amdgcn_mfma_f32_16x16x32_bf16(af1, w1, accB1, 0, 0, 0);
        accA2 = __builtin_amdgcn_mfma_f32_16x16x32_bf16(af0, w2, accA2, 0, 0, 0);
        accB2 = __builtin_amdgcn_mfma_f32_16x16x32_bf16(af1, w2, accB2, 0, 0, 0);
        accA3 = __builtin_amdgcn_mfma_f32_16x16x32_bf16(af0, w3, accA3, 0, 0, 0);
        accB3 = __builtin_amdgcn_mfma_f32_16x16x32_bf16(af1, w3, accB3, 0, 0, 0);
    }

    // C/D layout: lane holds D[row = q*4+i][col = lane&15]; row = sample-in-tile
#pragma unroll
    for (int i = 0; i < 4; ++i) {
        const int r0 = q * 4 + i;
        lds[h][c][r0][ 0 + mcol] = accA0[i];
        lds[h][c][r0][16 + mcol] = accA1[i];
        lds[h][c][r0][32 + mcol] = accA2[i];
        lds[h][c][r0][48 + mcol] = accA3[i];
        lds[h][c][16 + r0][ 0 + mcol] = accB0[i];
        lds[h][c][16 + r0][16 + mcol] = accB1[i];
        lds[h][c][16 + r0][32 + mcol] = accB2[i];
        lds[h][c][16 + r0][48 + mcol] = accB3[i];
    }
    __syncthreads();

    if (tid < 256) {
        const int mm = tid >> 3;          // sample within block (0..31)
        const int b  = tid & 7;           // bond index b
        const size_t k = (size_t)blk * 32 + mm;
        const float* xr = x + k * ROWLEN;
        const float x0 = xr[0],    x1 = xr[1];        // x[k, 0, :]
        const float y0 = xr[4094], y1 = xr[4095];     // x[k, 2047, :]
        // boundary vectors inline (row 2 normalized), wave-uniform loads
        const float lbn = 1.0f / sqrtf(left_b[4]*left_b[4] + left_b[5]*left_b[5]);
        const float rbn = 1.0f / sqrtf(right_b[4]*right_b[4] + right_b[5]*right_b[5]);
        float l = 0.f, r = 0.f;
#pragma unroll
        for (int a = 0; a < 8; ++a) {
            float lv = left_b[a*2]  * x0 + left_b[a*2+1]  * x1;
            float rv = right_b[a*2] * y0 + right_b[a*2+1] * y1;
            if (a == 2) { lv *= lbn; rv *= rbn; }
            const int n = a * 8 + b;
            const float ls = lds[0][0][mm][n] + lds[0][1][mm][n]
                           + lds[0][2][mm][n] + lds[0][3][mm][n];
            const float rs = lds[1][0][mm][n] + lds[1][1][mm][n]
                           + lds[1][2][mm][n] + lds[1][3][mm][n];
            l += lv * ls;
            r += rv * rs;
        }
        float vv = l * r;
        vv += __shfl_xor(vv, 1);
        vv += __shfl_xor(vv, 2);
        vv += __shfl_xor(vv, 4);
        if (b == 0) out[k] = vv;
    }
}

extern "C" void kernel_launch(void* const* d_in, const int* in_sizes, int n_in,
                              void* d_out, int out_size, void* d_ws, size_t ws_size,
                              hipStream_t stream)
{
    const float* x       = (const float*)d_in[0];
    const float* left_b  = (const float*)d_in[1];
    const float* left    = (const float*)d_in[2];
    const float* right   = (const float*)d_in[3];
    const float* right_b = (const float*)d_in[4];

    __bf16* wfrag = (__bf16*)d_ws;
    float*  out   = (float*)d_out;

    hipLaunchKernelGGL(repack_kernel, dim3(128), dim3(256), 0, stream,
                       left, right, wfrag);
    hipLaunchKernelGGL(mps_main_kernel, dim3(B_SAMPLES / 32), dim3(512), 0, stream,
                       x, wfrag, left_b, right_b, out);
}